// Round 1
// baseline (517.828 us; speedup 1.0000x reference)
//
#include <hip/hip_runtime.h>

// ScaledDotProductAttention: B=4, NQ=NK=2048, D_MODEL=D_K=D_V=1024, H=16, HD=64.
// Full bf16-MFMA pipeline (fp32 accumulate everywhere):
//  1) transpose_cast_w : W* fp32 [K][N] -> bf16 [N][K]   (B^T layout for MFMA B-frags)
//  2) proj_kernel      : Q/K/V projections, 128x128 tile, BK=32; epilogue scatters to
//                        Qh/Kh [B,H,N,64] and Vt [B,H,64,N] with per-32-key column
//                        INTERLEAVE (pos = quad*8+j*4+r) so attn V-frags are 16B loads.
//                        Q is PRE-SCALED by (1/sqrt(1024))*log2(e).
//  3) attn_kernel      : transposed-S flash attention, register-resident P
//                        (S^T C-layout == K-slot B-layout). Grid (bh,qy) for
//                        XCD L2 locality (R5: FETCH 141->36MB, confirmed).
//                        R6: VGPR_Count=60 proved the compiler sank the ping-pong
//                        prefetch AGAIN (needs >=128 resident) -> exposed L2 latency
//                        every subtile (MfmaUtil 17%). Now each prefetch block is
//                        pinned with sched_barrier(0) so the 8 next-subtile loads
//                        issue BEFORE process() and stay in registers (wait becomes
//                        vmcnt(8)). PV now a single K=32 MFMA: the Vt interleave makes
//                        pf[0]||pf[1] exactly the 16x16x32 B-fragment for the s16x8
//                        V row (same logical k-slot permutation on both operands).
//                        s_setprio(1) wraps the MFMA clusters (T5).
//  4) out_kernel       : O @ Wo + bo -> fp32 d_out
// Workspace: 72 MiB total (offsets below).

#define DM    1024
#define NSEQ  2048
#define HEADS 16
#define HD    64

typedef float floatx4 __attribute__((ext_vector_type(4)));
typedef short s16x4   __attribute__((ext_vector_type(4)));
typedef short s16x8   __attribute__((ext_vector_type(8)));
typedef unsigned int u32x4 __attribute__((ext_vector_type(4)));

static __device__ __forceinline__ floatx4 mfma_bf16(s16x8 a, s16x8 b, floatx4 c) {
  return __builtin_amdgcn_mfma_f32_16x16x32_bf16(a, b, c, 0, 0, 0);
}

// fp32 -> bf16 round-to-nearest-even (bit trick; inputs are finite)
static __device__ __forceinline__ short f2bf(float f) {
  unsigned u = __builtin_bit_cast(unsigned, f);
  u += 0x7FFFu + ((u >> 16) & 1u);
  return (short)(u >> 16);
}

// Pack 2 fp32 -> 2 bf16 in one u32 (round-half-up: +0x8000, keep high halves).
static __device__ __forceinline__ unsigned pack2_bf16(float a, float b) {
  unsigned ua = __builtin_bit_cast(unsigned, a) + 0x8000u;
  unsigned ub = __builtin_bit_cast(unsigned, b) + 0x8000u;
#if __has_builtin(__builtin_amdgcn_perm)
  return __builtin_amdgcn_perm(ub, ua, 0x07060302u);  // lo=hi16(ua), hi=hi16(ub)
#else
  return (ub & 0xffff0000u) | (ua >> 16);
#endif
}

// ---------------------------------------------------------------------------
// 1) Weight transpose + cast: W [1024 k][1024 n] fp32 -> Wt [n][k] bf16
__global__ __launch_bounds__(256) void transpose_cast_w(
    const float* __restrict__ W0, const float* __restrict__ W1,
    const float* __restrict__ W2, const float* __restrict__ W3,
    short* __restrict__ T0, short* __restrict__ T1,
    short* __restrict__ T2, short* __restrict__ T3) {
  __shared__ float tile[32][33];
  const float* W = blockIdx.z == 0 ? W0 : blockIdx.z == 1 ? W1 : blockIdx.z == 2 ? W2 : W3;
  short*       T = blockIdx.z == 0 ? T0 : blockIdx.z == 1 ? T1 : blockIdx.z == 2 ? T2 : T3;
  const int bx = blockIdx.x * 32;  // n-offset
  const int by = blockIdx.y * 32;  // k-offset
  const int tx = threadIdx.x, ty = threadIdx.y;
  for (int i = 0; i < 4; i++)
    tile[ty + i * 8][tx] = W[(long)(by + ty + i * 8) * DM + bx + tx];
  __syncthreads();
  for (int i = 0; i < 4; i++)
    T[(long)(bx + ty + i * 8) * DM + by + tx] = f2bf(tile[tx][ty + i * 8]);
}

// ---------------------------------------------------------------------------
// 2) Projection GEMM: C[8192x1024] = A(fp32) @ W, A staged fp32->bf16.
//    z=0: queries->Qh (PRE-SCALED by log2e/sqrt(d_k)), z=1: keys->Kh, z=2: values->Vt
__global__ __launch_bounds__(256) void proj_kernel(
    const float* __restrict__ Aq, const float* __restrict__ Ak, const float* __restrict__ Av,
    const short* __restrict__ BtQ, const short* __restrict__ BtK, const short* __restrict__ BtV,
    short* __restrict__ Qh, short* __restrict__ Kh, short* __restrict__ Vt) {
  __shared__ short As[128 * 40];  // 128 rows x (32+8 pad) bf16
  __shared__ short Bs[128 * 40];
  const int z = blockIdx.z;
  const float* A  = z == 0 ? Aq  : z == 1 ? Ak  : Av;
  const short* Bt = z == 0 ? BtQ : z == 1 ? BtK : BtV;
  const int t = threadIdx.x;
  const int w = t >> 6, l = t & 63, quad = l >> 4, lm = l & 15;
  const int wm = w >> 1, wn = w & 1;
  const int row0 = blockIdx.x * 128, col0 = blockIdx.y * 128;

  floatx4 acc[4][4];
  for (int mi = 0; mi < 4; mi++)
    for (int ni = 0; ni < 4; ni++) acc[mi][ni] = (floatx4){0.f, 0.f, 0.f, 0.f};

  for (int k0 = 0; k0 < DM; k0 += 32) {
    for (int j = 0; j < 4; j++) {  // A tile: 128x32 fp32 -> bf16 LDS
      int idx = j * 256 + t;
      int row = idx >> 3, c4 = idx & 7;
      floatx4 v = *(const floatx4*)(A + (long)(row0 + row) * DM + k0 + c4 * 4);
      s16x4 hv = {f2bf(v[0]), f2bf(v[1]), f2bf(v[2]), f2bf(v[3])};
      *(s16x4*)(As + row * 40 + c4 * 4) = hv;
    }
    for (int j = 0; j < 2; j++) {  // B tile: 128x32 bf16
      int idx = j * 256 + t;
      int row = idx >> 2, ch = idx & 3;
      *(s16x8*)(Bs + row * 40 + ch * 8) =
          *(const s16x8*)(Bt + (long)(col0 + row) * DM + k0 + ch * 8);
    }
    __syncthreads();
    s16x8 af[4], bfr[4];
    for (int mi = 0; mi < 4; mi++)
      af[mi] = *(const s16x8*)(As + (wm * 64 + mi * 16 + lm) * 40 + quad * 8);
    for (int ni = 0; ni < 4; ni++)
      bfr[ni] = *(const s16x8*)(Bs + (wn * 64 + ni * 16 + lm) * 40 + quad * 8);
    for (int mi = 0; mi < 4; mi++)
      for (int ni = 0; ni < 4; ni++)
        acc[mi][ni] = mfma_bf16(af[mi], bfr[ni], acc[mi][ni]);
    __syncthreads();
  }

  const int rowbase = row0 + wm * 64;  // multiple of 64 -> single b per wave
  const int colbase = col0 + wn * 64;  // multiple of 64 -> single head per wave
  const int b = rowbase >> 11;
  const int h = colbase >> 6;
  const int rloc = rowbase & 2047;
  if (z < 2) {
    short* Out = z == 0 ? Qh : Kh;
    // Fold softmax scale * log2(e) into Q so attn uses exp2 with no multiply.
    const float osc = z == 0 ? 0.0450842200277801f : 1.0f;
    long base = ((long)(b * HEADS + h)) * NSEQ * HD;
    for (int mi = 0; mi < 4; mi++)
      for (int r = 0; r < 4; r++) {
        int q = rloc + mi * 16 + quad * 4 + r;
        long rowoff = base + (long)q * HD + lm;
        for (int ni = 0; ni < 4; ni++)
          Out[rowoff + ni * 16] = f2bf(acc[mi][ni][r] * osc);
      }
  } else {
    // Vt with per-32-key interleave: key kloc=(j*16+quad*4+r) within its 32-group
    // is stored at position quad*8 + j*4 + r, so attn reads one 16B chunk per
    // (d-row, quad) covering a full K=32 logical-k fragment.
    long base = ((long)(b * HEADS + h)) * HD * NSEQ;
    for (int mi = 0; mi < 4; mi++)
      for (int r = 0; r < 4; r++) {
        int kcol = rloc + (mi >> 1) * 32 + quad * 8 + (mi & 1) * 4 + r;
        for (int ni = 0; ni < 4; ni++)
          Vt[base + (long)(ni * 16 + lm) * NSEQ + kcol] = f2bf(acc[mi][ni][r]);
      }
  }
}

// ---------------------------------------------------------------------------
// 3) Transposed-S flash attention. Grid (bh=64, qy=16) -> XCD = bh%8 (L2 local).
//    4 waves/block, wave = 32 q-rows (2x16), 32 keys/subtile, 64 keys/iter.
//    Double-buffered K AND V in named registers; prefetch blocks pinned with
//    sched_barrier(0) so the 8 next-subtile loads issue before process() and
//    the steady-state wait is vmcnt(8) (R6: without the fence the scheduler
//    sank the loads -> VGPR_Count=60 -> serial L2 latency per subtile).
//    PV is a single 16x16x32 MFMA per (qi,n): interleaved Vt row (s16x8) as A,
//    pf[0]||pf[1] as B -- logical k-slot e of both operands maps to key
//    (e>>2)*16 + quad*4 + (e&3), so the contraction is exact.
__global__ __launch_bounds__(256, 2) void attn_kernel(
    const short* __restrict__ Qh, const short* __restrict__ Kh,
    const short* __restrict__ Vt, short* __restrict__ Obf) {
  __shared__ short Olds[4][16 * 72];  // per-wave 16q x (64+8 pad) epilogue tile
  const int t = threadIdx.x;
  const int w = t >> 6, l = t & 63, quad = l >> 4, lm = l & 15;
  const int bh = blockIdx.x;    // b*16+h  (grid-x => XCD = bh%8: L2 locality)
  const int qtile = blockIdx.y * 128 + w * 32;
  const short* Qp = Qh + (long)bh * NSEQ * HD;
  const short* Kp = Kh + (long)bh * NSEQ * HD;
  const short* Vp = Vt + (long)bh * HD * NSEQ;

  s16x8 aq[2][2];  // Q-frags; serve as MFMA *B* operand for S^T (layout identical)
#pragma unroll
  for (int qi = 0; qi < 2; qi++)
#pragma unroll
    for (int c = 0; c < 2; c++)
      aq[qi][c] = *(const s16x8*)(Qp + (long)(qtile + qi * 16 + lm) * HD + c * 32 + quad * 8);

  floatx4 acc[2][4];  // O^T, C-layout: d = n*16+quad*4+reg, q = lm
  float lsum[2] = {0.f, 0.f};
#pragma unroll
  for (int qi = 0; qi < 2; qi++)
#pragma unroll
    for (int n = 0; n < 4; n++) acc[qi][n] = (floatx4){0.f, 0.f, 0.f, 0.f};

#define LOAD_K(dst, ktbase)                                                       \
  {                                                                               \
    _Pragma("unroll") for (int j = 0; j < 2; j++)                                 \
        _Pragma("unroll") for (int c = 0; c < 2; c++)                             \
            dst[j][c] = *(const s16x8*)(Kp + (long)((ktbase) + j * 16 + lm) * HD  \
                                        + c * 32 + quad * 8);                     \
  }
#define LOAD_V(dst, ktbase)                                                       \
  {                                                                               \
    _Pragma("unroll") for (int n = 0; n < 4; n++)                                 \
        dst[n] = *(const s16x8*)(Vp + (long)(n * 16 + lm) * NSEQ + (ktbase)       \
                                 + quad * 8);                                     \
  }

  s16x8 kA[2][2], kB[2][2];   // K ping-pong
  s16x8 vA[4], vB[4];         // V ping-pong (interleaved Vt: 16B per d-tile)
  LOAD_K(kA, 0);
  LOAD_V(vA, 0);
  __builtin_amdgcn_sched_barrier(0);

  auto process = [&](s16x8 (&bk)[2][2], s16x8 (&vraw)[4])
      __attribute__((always_inline)) {
#pragma unroll
    for (int qi = 0; qi < 2; qi++) {
      floatx4 sT[2];
      sT[0] = (floatx4){0.f, 0.f, 0.f, 0.f};
      sT[1] = (floatx4){0.f, 0.f, 0.f, 0.f};
      __builtin_amdgcn_s_setprio(1);
#pragma unroll
      for (int c = 0; c < 2; c++) {
        sT[0] = mfma_bf16(bk[0][c], aq[qi][c], sT[0]);
        sT[1] = mfma_bf16(bk[1][c], aq[qi][c], sT[1]);
      }
      __builtin_amdgcn_s_setprio(0);
      float p0 = __builtin_amdgcn_exp2f(sT[0][0]);
      float p1 = __builtin_amdgcn_exp2f(sT[0][1]);
      float p2 = __builtin_amdgcn_exp2f(sT[0][2]);
      float p3 = __builtin_amdgcn_exp2f(sT[0][3]);
      float p4 = __builtin_amdgcn_exp2f(sT[1][0]);
      float p5 = __builtin_amdgcn_exp2f(sT[1][1]);
      float p6 = __builtin_amdgcn_exp2f(sT[1][2]);
      float p7 = __builtin_amdgcn_exp2f(sT[1][3]);
      lsum[qi] += ((p0 + p1) + (p2 + p3)) + ((p4 + p5) + (p6 + p7));
      u32x4 pw = {pack2_bf16(p0, p1), pack2_bf16(p2, p3),
                  pack2_bf16(p4, p5), pack2_bf16(p6, p7)};
      s16x8 pcat = __builtin_bit_cast(s16x8, pw);
      __builtin_amdgcn_s_setprio(1);
#pragma unroll
      for (int n = 0; n < 4; n++)
        acc[qi][n] = mfma_bf16(vraw[n], pcat, acc[qi][n]);
      __builtin_amdgcn_s_setprio(0);
    }
  };

  for (int kt = 0; kt < NSEQ; kt += 64) {
    // prefetch subtile kt+32 into B buffers, THEN compute A: sched_barrier(0)
    // pins the issue order so the loads stay outstanding across process()
    // (its wait is vmcnt(8): only the OLDER kA/vA loads must land).
    LOAD_K(kB, kt + 32);
    LOAD_V(vB, kt + 32);
    __builtin_amdgcn_sched_barrier(0);
    process(kA, vA);
    const int ktn = (kt + 64 < NSEQ) ? kt + 64 : 0;  // uniform clamp (safe addr)
    LOAD_K(kA, ktn);
    LOAD_V(vA, ktn);
    __builtin_amdgcn_sched_barrier(0);
    process(kB, vB);
  }
#undef LOAD_K
#undef LOAD_V

  // lsum is per-lane over this lane's keys; full row sum = reduce across quads.
  const int b = bh >> 4, h = bh & 15;
  short* Ow = &Olds[w][0];
  const int erow = l >> 2, ecg = l & 3;  // epilogue read/store mapping
#pragma unroll
  for (int qi = 0; qi < 2; qi++) {
    float ls = lsum[qi];
    ls += __shfl_xor(ls, 16);
    ls += __shfl_xor(ls, 32);
    float rl = 1.0f / ls;  // row sum for q = lm (same for all regs)
#pragma unroll
    for (int n = 0; n < 4; n++)
#pragma unroll
      for (int r = 0; r < 4; r++)
        Ow[lm * 72 + n * 16 + quad * 4 + r] = f2bf(acc[qi][n][r] * rl);
    // read back row-major (same wave; compiler inserts lgkmcnt wait), store coalesced
    s16x8 o0 = *(const s16x8*)(Ow + erow * 72 + ecg * 16);
    s16x8 o1 = *(const s16x8*)(Ow + erow * 72 + ecg * 16 + 8);
    long gaddr = ((long)(b * NSEQ + qtile + qi * 16 + erow)) * DM + h * HD + ecg * 16;
    *(s16x8*)(Obf + gaddr) = o0;
    *(s16x8*)(Obf + gaddr + 8) = o1;
  }
}

// ---------------------------------------------------------------------------
// 4) Output GEMM: d_out = Obf(bf16) @ WoT + bo, fp32 out
__global__ __launch_bounds__(256) void out_kernel(
    const short* __restrict__ Ab, const short* __restrict__ Bt,
    const float* __restrict__ bias, float* __restrict__ Out) {
  __shared__ short As[128 * 40];
  __shared__ short Bs[128 * 40];
  const int t = threadIdx.x;
  const int w = t >> 6, l = t & 63, quad = l >> 4, lm = l & 15;
  const int wm = w >> 1, wn = w & 1;
  const int row0 = blockIdx.x * 128, col0 = blockIdx.y * 128;

  floatx4 acc[4][4];
  for (int mi = 0; mi < 4; mi++)
    for (int ni = 0; ni < 4; ni++) acc[mi][ni] = (floatx4){0.f, 0.f, 0.f, 0.f};

  for (int k0 = 0; k0 < DM; k0 += 32) {
    for (int j = 0; j < 2; j++) {
      int idx = j * 256 + t;
      int row = idx >> 2, ch = idx & 3;
      *(s16x8*)(As + row * 40 + ch * 8) =
          *(const s16x8*)(Ab + (long)(row0 + row) * DM + k0 + ch * 8);
    }
    for (int j = 0; j < 2; j++) {
      int idx = j * 256 + t;
      int row = idx >> 2, ch = idx & 3;
      *(s16x8*)(Bs + row * 40 + ch * 8) =
          *(const s16x8*)(Bt + (long)(col0 + row) * DM + k0 + ch * 8);
    }
    __syncthreads();
    s16x8 af[4], bfr[4];
    for (int mi = 0; mi < 4; mi++)
      af[mi] = *(const s16x8*)(As + (wm * 64 + mi * 16 + lm) * 40 + quad * 8);
    for (int ni = 0; ni < 4; ni++)
      bfr[ni] = *(const s16x8*)(Bs + (wn * 64 + ni * 16 + lm) * 40 + quad * 8);
    for (int mi = 0; mi < 4; mi++)
      for (int ni = 0; ni < 4; ni++)
        acc[mi][ni] = mfma_bf16(af[mi], bfr[ni], acc[mi][ni]);
    __syncthreads();
  }

  const int rowbase = row0 + wm * 64;
  const int colbase = col0 + wn * 64;
  for (int mi = 0; mi < 4; mi++)
    for (int r = 0; r < 4; r++) {
      int gr = rowbase + mi * 16 + quad * 4 + r;
      for (int ni = 0; ni < 4; ni++) {
        int gc = colbase + ni * 16 + lm;
        Out[(long)gr * DM + gc] = acc[mi][ni][r] + bias[gc];
      }
    }
}

// ---------------------------------------------------------------------------
extern "C" void kernel_launch(void* const* d_in, const int* in_sizes, int n_in,
                              void* d_out, int out_size, void* d_ws, size_t ws_size,
                              hipStream_t stream) {
  (void)in_sizes; (void)n_in; (void)out_size; (void)ws_size;
  const float* queries = (const float*)d_in[0];
  const float* keys    = (const float*)d_in[1];
  const float* values  = (const float*)d_in[2];
  const float* Wq = (const float*)d_in[3];
  const float* Wk = (const float*)d_in[4];
  const float* Wv = (const float*)d_in[5];
  const float* Wo = (const float*)d_in[6];
  const float* bo = (const float*)d_in[7];
  float* out = (float*)d_out;

  char* ws = (char*)d_ws;
  const size_t MB = 1024 * 1024;
  short* WqT = (short*)(ws + 0 * MB);   // 2 MiB each
  short* WkT = (short*)(ws + 2 * MB);
  short* WvT = (short*)(ws + 4 * MB);
  short* WoT = (short*)(ws + 6 * MB);
  short* Qh  = (short*)(ws + 8 * MB);   // [B,H,2048,64] bf16 = 16 MiB
  short* Kh  = (short*)(ws + 24 * MB);  // 16 MiB
  short* Vt  = (short*)(ws + 40 * MB);  // [B,H,64,2048] bf16 (interleaved cols) = 16 MiB
  short* Obf = (short*)(ws + 56 * MB);  // [8192,1024] bf16 = 16 MiB  (total 72 MiB)

  transpose_cast_w<<<dim3(32, 32, 4), dim3(32, 8), 0, stream>>>(
      Wq, Wk, Wv, Wo, WqT, WkT, WvT, WoT);
  proj_kernel<<<dim3(64, 8, 3), 256, 0, stream>>>(
      queries, keys, values, WqT, WkT, WvT, Qh, Kh, Vt);
  attn_kernel<<<dim3(64, 16), 256, 0, stream>>>(Qh, Kh, Vt, Obf);
  out_kernel<<<dim3(64, 8), 256, 0, stream>>>(Obf, WoT, bo, out);
}

// Round 2
// 467.076 us; speedup vs baseline: 1.1087x; 1.1087x over previous
//
#include <hip/hip_runtime.h>

// ScaledDotProductAttention: B=4, NQ=NK=2048, D_MODEL=D_K=D_V=1024, H=16, HD=64.
// Full bf16-MFMA pipeline (fp32 accumulate everywhere):
//  1) transpose_cast_w : W* fp32 [K][N] -> bf16 [N][K]   (B^T layout for MFMA B-frags)
//  2) proj_kernel      : Q/K/V projections, 128x128 tile, BK=32; epilogue scatters to
//                        Qh/Kh [B,H,N,64] and Vt [B,H,64,N] with per-32-key column
//                        INTERLEAVE (pos = quad*8+j*4+r) so attn V-frags are 16B loads.
//                        Q is PRE-SCALED by (1/sqrt(1024))*log2(e).
//  3) attn_kernel      : transposed-S flash attention, register-resident P.
//                        R6 history: register K/V ping-pong (R5/R6) was stall-bound at
//                        ~246us regardless of scheduling -- root cause: all 4 waves
//                        loaded the IDENTICAL K/V tile (loads depend only on lane),
//                        4x redundant VMEM, per-wave L2 latency exposed every subtile
//                        (MfmaUtil 11-17%, occupancy-insensitive).
//                        R7: block-shared staging via global_load_lds into LDS,
//                        FRAGMENT-MAJOR layout: 16 groups x 1KiB per 64-key tile
//                        (8 K-frag groups, 8 V-frag groups); per-lane global source
//                        address = exactly the 16B that lane's ds_read_b128 consumes,
//                        LDS dest linear (base+lane*16, the HW rule). Reads are
//                        group*1KiB + lane*16 -> conflict-free, no swizzle.
//                        4 gload_lds per wave per tile (was 24 flat dwordx4), issued
//                        before process() so the pre-barrier vmcnt drain is hidden
//                        under ~600cy of MFMA+exp2 (T3 minimum 2-phase).
//  4) out_kernel       : O @ Wo + bo -> fp32 d_out
// Workspace: 72 MiB total (offsets below).

#define DM    1024
#define NSEQ  2048
#define HEADS 16
#define HD    64

typedef float floatx4 __attribute__((ext_vector_type(4)));
typedef short s16x4   __attribute__((ext_vector_type(4)));
typedef short s16x8   __attribute__((ext_vector_type(8)));
typedef unsigned int u32x4 __attribute__((ext_vector_type(4)));

static __device__ __forceinline__ floatx4 mfma_bf16(s16x8 a, s16x8 b, floatx4 c) {
  return __builtin_amdgcn_mfma_f32_16x16x32_bf16(a, b, c, 0, 0, 0);
}

// Async global->LDS DMA, 16B per lane: dest = wave-uniform base + lane*16,
// source = per-lane global address.
static __device__ __forceinline__ void gload_lds16(const void* g, void* l) {
  __builtin_amdgcn_global_load_lds(
      (const __attribute__((address_space(1))) unsigned*)g,
      (__attribute__((address_space(3))) unsigned*)l, 16, 0, 0);
}

// fp32 -> bf16 round-to-nearest-even (bit trick; inputs are finite)
static __device__ __forceinline__ short f2bf(float f) {
  unsigned u = __builtin_bit_cast(unsigned, f);
  u += 0x7FFFu + ((u >> 16) & 1u);
  return (short)(u >> 16);
}

// Pack 2 fp32 -> 2 bf16 in one u32 (round-half-up: +0x8000, keep high halves).
static __device__ __forceinline__ unsigned pack2_bf16(float a, float b) {
  unsigned ua = __builtin_bit_cast(unsigned, a) + 0x8000u;
  unsigned ub = __builtin_bit_cast(unsigned, b) + 0x8000u;
#if __has_builtin(__builtin_amdgcn_perm)
  return __builtin_amdgcn_perm(ub, ua, 0x07060302u);  // lo=hi16(ua), hi=hi16(ub)
#else
  return (ub & 0xffff0000u) | (ua >> 16);
#endif
}

// ---------------------------------------------------------------------------
// 1) Weight transpose + cast: W [1024 k][1024 n] fp32 -> Wt [n][k] bf16
__global__ __launch_bounds__(256) void transpose_cast_w(
    const float* __restrict__ W0, const float* __restrict__ W1,
    const float* __restrict__ W2, const float* __restrict__ W3,
    short* __restrict__ T0, short* __restrict__ T1,
    short* __restrict__ T2, short* __restrict__ T3) {
  __shared__ float tile[32][33];
  const float* W = blockIdx.z == 0 ? W0 : blockIdx.z == 1 ? W1 : blockIdx.z == 2 ? W2 : W3;
  short*       T = blockIdx.z == 0 ? T0 : blockIdx.z == 1 ? T1 : blockIdx.z == 2 ? T2 : T3;
  const int bx = blockIdx.x * 32;  // n-offset
  const int by = blockIdx.y * 32;  // k-offset
  const int tx = threadIdx.x, ty = threadIdx.y;
  for (int i = 0; i < 4; i++)
    tile[ty + i * 8][tx] = W[(long)(by + ty + i * 8) * DM + bx + tx];
  __syncthreads();
  for (int i = 0; i < 4; i++)
    T[(long)(bx + ty + i * 8) * DM + by + tx] = f2bf(tile[tx][ty + i * 8]);
}

// ---------------------------------------------------------------------------
// 2) Projection GEMM: C[8192x1024] = A(fp32) @ W, A staged fp32->bf16.
//    z=0: queries->Qh (PRE-SCALED by log2e/sqrt(d_k)), z=1: keys->Kh, z=2: values->Vt
__global__ __launch_bounds__(256) void proj_kernel(
    const float* __restrict__ Aq, const float* __restrict__ Ak, const float* __restrict__ Av,
    const short* __restrict__ BtQ, const short* __restrict__ BtK, const short* __restrict__ BtV,
    short* __restrict__ Qh, short* __restrict__ Kh, short* __restrict__ Vt) {
  __shared__ short As[128 * 40];  // 128 rows x (32+8 pad) bf16
  __shared__ short Bs[128 * 40];
  const int z = blockIdx.z;
  const float* A  = z == 0 ? Aq  : z == 1 ? Ak  : Av;
  const short* Bt = z == 0 ? BtQ : z == 1 ? BtK : BtV;
  const int t = threadIdx.x;
  const int w = t >> 6, l = t & 63, quad = l >> 4, lm = l & 15;
  const int wm = w >> 1, wn = w & 1;
  const int row0 = blockIdx.x * 128, col0 = blockIdx.y * 128;

  floatx4 acc[4][4];
  for (int mi = 0; mi < 4; mi++)
    for (int ni = 0; ni < 4; ni++) acc[mi][ni] = (floatx4){0.f, 0.f, 0.f, 0.f};

  for (int k0 = 0; k0 < DM; k0 += 32) {
    for (int j = 0; j < 4; j++) {  // A tile: 128x32 fp32 -> bf16 LDS
      int idx = j * 256 + t;
      int row = idx >> 3, c4 = idx & 7;
      floatx4 v = *(const floatx4*)(A + (long)(row0 + row) * DM + k0 + c4 * 4);
      s16x4 hv = {f2bf(v[0]), f2bf(v[1]), f2bf(v[2]), f2bf(v[3])};
      *(s16x4*)(As + row * 40 + c4 * 4) = hv;
    }
    for (int j = 0; j < 2; j++) {  // B tile: 128x32 bf16
      int idx = j * 256 + t;
      int row = idx >> 2, ch = idx & 3;
      *(s16x8*)(Bs + row * 40 + ch * 8) =
          *(const s16x8*)(Bt + (long)(col0 + row) * DM + k0 + ch * 8);
    }
    __syncthreads();
    s16x8 af[4], bfr[4];
    for (int mi = 0; mi < 4; mi++)
      af[mi] = *(const s16x8*)(As + (wm * 64 + mi * 16 + lm) * 40 + quad * 8);
    for (int ni = 0; ni < 4; ni++)
      bfr[ni] = *(const s16x8*)(Bs + (wn * 64 + ni * 16 + lm) * 40 + quad * 8);
    for (int mi = 0; mi < 4; mi++)
      for (int ni = 0; ni < 4; ni++)
        acc[mi][ni] = mfma_bf16(af[mi], bfr[ni], acc[mi][ni]);
    __syncthreads();
  }

  const int rowbase = row0 + wm * 64;  // multiple of 64 -> single b per wave
  const int colbase = col0 + wn * 64;  // multiple of 64 -> single head per wave
  const int b = rowbase >> 11;
  const int h = colbase >> 6;
  const int rloc = rowbase & 2047;
  if (z < 2) {
    short* Out = z == 0 ? Qh : Kh;
    // Fold softmax scale * log2(e) into Q so attn uses exp2 with no multiply.
    const float osc = z == 0 ? 0.0450842200277801f : 1.0f;
    long base = ((long)(b * HEADS + h)) * NSEQ * HD;
    for (int mi = 0; mi < 4; mi++)
      for (int r = 0; r < 4; r++) {
        int q = rloc + mi * 16 + quad * 4 + r;
        long rowoff = base + (long)q * HD + lm;
        for (int ni = 0; ni < 4; ni++)
          Out[rowoff + ni * 16] = f2bf(acc[mi][ni][r] * osc);
      }
  } else {
    // Vt with per-32-key interleave: key kloc=(j*16+quad*4+r) within its 32-group
    // is stored at position quad*8 + j*4 + r, so attn reads one 16B chunk per
    // (d-row, quad) covering a full K=32 logical-k fragment.
    long base = ((long)(b * HEADS + h)) * HD * NSEQ;
    for (int mi = 0; mi < 4; mi++)
      for (int r = 0; r < 4; r++) {
        int kcol = rloc + (mi >> 1) * 32 + quad * 8 + (mi & 1) * 4 + r;
        for (int ni = 0; ni < 4; ni++)
          Vt[base + (long)(ni * 16 + lm) * NSEQ + kcol] = f2bf(acc[mi][ni][r]);
      }
  }
}

// ---------------------------------------------------------------------------
// 3) Transposed-S flash attention. Grid (bh=64, qy=16) -> XCD = bh%8 (L2 local).
//    4 waves/block, wave = 32 q-rows (2x16); K/V tile (64 keys) staged ONCE per
//    block in LDS (was: every wave loaded it redundantly).
//    LDS layout per tile buffer: 16 groups x 1KiB, fragment-major:
//      g = 0..7  : K frag group (s=g>>2, j=(g>>1)&1, c=g&1); chunk l holds the 16B
//                  K[kt+s*32+j*16+(l&15)][c*32+(l>>4)*8 ..+8]
//      g = 8..15 : V frag group (s=(g&7)>>2, n=g&3); chunk l holds the 16B
//                  Vt[n*16+(l&15)][kt+s*32+(l>>4)*8 ..+8]   (interleaved cols)
//    Staged via global_load_lds (dest = base+lane*16, per-lane source address),
//    4 instructions per wave per tile. ds_read_b128 back at group*1K + l*16:
//    linear in lane -> conflict-free. Double-buffered; stage(next) is issued
//    before process(cur) so the __syncthreads vmcnt drain is hidden (T3 2-phase).
__global__ __launch_bounds__(256, 4) void attn_kernel(
    const short* __restrict__ Qh, const short* __restrict__ Kh,
    const short* __restrict__ Vt, short* __restrict__ Obf) {
  __shared__ short lds[2 * 8192];  // 2 x 16KiB tile buffers; epilogue reuses buf0
  const int t = threadIdx.x;
  const int w = t >> 6, l = t & 63, quad = l >> 4, lm = l & 15;
  const int bh = blockIdx.x;    // b*16+h  (grid-x => XCD = bh%8: L2 locality)
  const int qtile = blockIdx.y * 128 + w * 32;
  const short* Qp = Qh + (long)bh * NSEQ * HD;
  const short* Kp = Kh + (long)bh * NSEQ * HD;
  const short* Vp = Vt + (long)bh * HD * NSEQ;

  s16x8 aq[2][2];  // Q-frags; serve as MFMA *B* operand for S^T (layout identical)
#pragma unroll
  for (int qi = 0; qi < 2; qi++)
#pragma unroll
    for (int c = 0; c < 2; c++)
      aq[qi][c] = *(const s16x8*)(Qp + (long)(qtile + qi * 16 + lm) * HD + c * 32 + quad * 8);

  floatx4 acc[2][4];  // O^T, C-layout: d = n*16+quad*4+reg, q = lm
  float lsum[2] = {0.f, 0.f};
#pragma unroll
  for (int qi = 0; qi < 2; qi++)
#pragma unroll
    for (int n = 0; n < 4; n++) acc[qi][n] = (floatx4){0.f, 0.f, 0.f, 0.f};

  // Stage the 64-key tile at kt into buffer `buf`. Wave w stages groups 4w..4w+3.
  auto stage = [&](int kt, int buf) __attribute__((always_inline)) {
    short* base = lds + buf * 8192;
#pragma unroll
    for (int i = 0; i < 4; i++) {
      int g = w * 4 + i;
      const short* src;
      if (w < 2) {  // K groups 0..7
        int s = (g >> 2) & 1, j = (g >> 1) & 1, c = g & 1;
        src = Kp + (long)(kt + s * 32 + j * 16 + lm) * HD + c * 32 + quad * 8;
      } else {      // V groups 8..15
        int gg = g & 7;
        int s = gg >> 2, n = gg & 3;
        src = Vp + (long)(n * 16 + lm) * NSEQ + kt + s * 32 + quad * 8;
      }
      gload_lds16(src, base + g * 512);
    }
  };

  // Process one 32-key subtile (s = 0/1) from tile buffer Lb.
  auto process = [&](const short* Lb, int s) __attribute__((always_inline)) {
    s16x8 bk[2][2];
#pragma unroll
    for (int j = 0; j < 2; j++)
#pragma unroll
      for (int c = 0; c < 2; c++)
        bk[j][c] = *(const s16x8*)(Lb + ((s * 4 + j * 2 + c) * 64 + l) * 8);
    s16x8 vraw[4];
#pragma unroll
    for (int n = 0; n < 4; n++)
      vraw[n] = *(const s16x8*)(Lb + ((8 + s * 4 + n) * 64 + l) * 8);
#pragma unroll
    for (int qi = 0; qi < 2; qi++) {
      floatx4 sT[2];
      sT[0] = (floatx4){0.f, 0.f, 0.f, 0.f};
      sT[1] = (floatx4){0.f, 0.f, 0.f, 0.f};
      __builtin_amdgcn_s_setprio(1);
#pragma unroll
      for (int c = 0; c < 2; c++) {
        sT[0] = mfma_bf16(bk[0][c], aq[qi][c], sT[0]);
        sT[1] = mfma_bf16(bk[1][c], aq[qi][c], sT[1]);
      }
      __builtin_amdgcn_s_setprio(0);
      float p0 = __builtin_amdgcn_exp2f(sT[0][0]);
      float p1 = __builtin_amdgcn_exp2f(sT[0][1]);
      float p2 = __builtin_amdgcn_exp2f(sT[0][2]);
      float p3 = __builtin_amdgcn_exp2f(sT[0][3]);
      float p4 = __builtin_amdgcn_exp2f(sT[1][0]);
      float p5 = __builtin_amdgcn_exp2f(sT[1][1]);
      float p6 = __builtin_amdgcn_exp2f(sT[1][2]);
      float p7 = __builtin_amdgcn_exp2f(sT[1][3]);
      lsum[qi] += ((p0 + p1) + (p2 + p3)) + ((p4 + p5) + (p6 + p7));
      u32x4 pw = {pack2_bf16(p0, p1), pack2_bf16(p2, p3),
                  pack2_bf16(p4, p5), pack2_bf16(p6, p7)};
      s16x8 pcat = __builtin_bit_cast(s16x8, pw);
      __builtin_amdgcn_s_setprio(1);
#pragma unroll
      for (int n = 0; n < 4; n++)
        acc[qi][n] = mfma_bf16(vraw[n], pcat, acc[qi][n]);
      __builtin_amdgcn_s_setprio(0);
    }
  };

  stage(0, 0);
  __syncthreads();  // compiler-emitted vmcnt(0) drain + s_barrier: tile 0 ready
  int cur = 0;
  for (int kt = 0; kt < NSEQ; kt += 64) {
    if (kt + 64 < NSEQ) stage(kt + 64, cur ^ 1);  // issue DMA, then compute
    const short* Lb = lds + cur * 8192;
    process(Lb, 0);
    process(Lb, 1);
    __syncthreads();  // drain (hidden under process) + cross-wave visibility
    cur ^= 1;
  }

  // lsum is per-lane over this lane's keys; full row sum = reduce across quads.
  const int b = bh >> 4, h = bh & 15;
  short* Ow = lds + w * 1152;  // reuse buf0 (final iter read buf1; regions disjoint)
  const int erow = l >> 2, ecg = l & 3;  // epilogue read/store mapping
#pragma unroll
  for (int qi = 0; qi < 2; qi++) {
    float ls = lsum[qi];
    ls += __shfl_xor(ls, 16);
    ls += __shfl_xor(ls, 32);
    float rl = 1.0f / ls;  // row sum for q = lm (same for all regs)
#pragma unroll
    for (int n = 0; n < 4; n++)
#pragma unroll
      for (int r = 0; r < 4; r++)
        Ow[lm * 72 + n * 16 + quad * 4 + r] = f2bf(acc[qi][n][r] * rl);
    // read back row-major (same wave; compiler inserts lgkmcnt wait), store coalesced
    s16x8 o0 = *(const s16x8*)(Ow + erow * 72 + ecg * 16);
    s16x8 o1 = *(const s16x8*)(Ow + erow * 72 + ecg * 16 + 8);
    long gaddr = ((long)(b * NSEQ + qtile + qi * 16 + erow)) * DM + h * HD + ecg * 16;
    *(s16x8*)(Obf + gaddr) = o0;
    *(s16x8*)(Obf + gaddr + 8) = o1;
  }
}

// ---------------------------------------------------------------------------
// 4) Output GEMM: d_out = Obf(bf16) @ WoT + bo, fp32 out
__global__ __launch_bounds__(256) void out_kernel(
    const short* __restrict__ Ab, const short* __restrict__ Bt,
    const float* __restrict__ bias, float* __restrict__ Out) {
  __shared__ short As[128 * 40];
  __shared__ short Bs[128 * 40];
  const int t = threadIdx.x;
  const int w = t >> 6, l = t & 63, quad = l >> 4, lm = l & 15;
  const int wm = w >> 1, wn = w & 1;
  const int row0 = blockIdx.x * 128, col0 = blockIdx.y * 128;

  floatx4 acc[4][4];
  for (int mi = 0; mi < 4; mi++)
    for (int ni = 0; ni < 4; ni++) acc[mi][ni] = (floatx4){0.f, 0.f, 0.f, 0.f};

  for (int k0 = 0; k0 < DM; k0 += 32) {
    for (int j = 0; j < 2; j++) {
      int idx = j * 256 + t;
      int row = idx >> 2, ch = idx & 3;
      *(s16x8*)(As + row * 40 + ch * 8) =
          *(const s16x8*)(Ab + (long)(row0 + row) * DM + k0 + ch * 8);
    }
    for (int j = 0; j < 2; j++) {
      int idx = j * 256 + t;
      int row = idx >> 2, ch = idx & 3;
      *(s16x8*)(Bs + row * 40 + ch * 8) =
          *(const s16x8*)(Bt + (long)(col0 + row) * DM + k0 + ch * 8);
    }
    __syncthreads();
    s16x8 af[4], bfr[4];
    for (int mi = 0; mi < 4; mi++)
      af[mi] = *(const s16x8*)(As + (wm * 64 + mi * 16 + lm) * 40 + quad * 8);
    for (int ni = 0; ni < 4; ni++)
      bfr[ni] = *(const s16x8*)(Bs + (wn * 64 + ni * 16 + lm) * 40 + quad * 8);
    for (int mi = 0; mi < 4; mi++)
      for (int ni = 0; ni < 4; ni++)
        acc[mi][ni] = mfma_bf16(af[mi], bfr[ni], acc[mi][ni]);
    __syncthreads();
  }

  const int rowbase = row0 + wm * 64;
  const int colbase = col0 + wn * 64;
  for (int mi = 0; mi < 4; mi++)
    for (int r = 0; r < 4; r++) {
      int gr = rowbase + mi * 16 + quad * 4 + r;
      for (int ni = 0; ni < 4; ni++) {
        int gc = colbase + ni * 16 + lm;
        Out[(long)gr * DM + gc] = acc[mi][ni][r] + bias[gc];
      }
    }
}

// ---------------------------------------------------------------------------
extern "C" void kernel_launch(void* const* d_in, const int* in_sizes, int n_in,
                              void* d_out, int out_size, void* d_ws, size_t ws_size,
                              hipStream_t stream) {
  (void)in_sizes; (void)n_in; (void)out_size; (void)ws_size;
  const float* queries = (const float*)d_in[0];
  const float* keys    = (const float*)d_in[1];
  const float* values  = (const float*)d_in[2];
  const float* Wq = (const float*)d_in[3];
  const float* Wk = (const float*)d_in[4];
  const float* Wv = (const float*)d_in[5];
  const float* Wo = (const float*)d_in[6];
  const float* bo = (const float*)d_in[7];
  float* out = (float*)d_out;

  char* ws = (char*)d_ws;
  const size_t MB = 1024 * 1024;
  short* WqT = (short*)(ws + 0 * MB);   // 2 MiB each
  short* WkT = (short*)(ws + 2 * MB);
  short* WvT = (short*)(ws + 4 * MB);
  short* WoT = (short*)(ws + 6 * MB);
  short* Qh  = (short*)(ws + 8 * MB);   // [B,H,2048,64] bf16 = 16 MiB
  short* Kh  = (short*)(ws + 24 * MB);  // 16 MiB
  short* Vt  = (short*)(ws + 40 * MB);  // [B,H,64,2048] bf16 (interleaved cols) = 16 MiB
  short* Obf = (short*)(ws + 56 * MB);  // [8192,1024] bf16 = 16 MiB  (total 72 MiB)

  transpose_cast_w<<<dim3(32, 32, 4), dim3(32, 8), 0, stream>>>(
      Wq, Wk, Wv, Wo, WqT, WkT, WvT, WoT);
  proj_kernel<<<dim3(64, 8, 3), 256, 0, stream>>>(
      queries, keys, values, WqT, WkT, WvT, Qh, Kh, Vt);
  attn_kernel<<<dim3(64, 16), 256, 0, stream>>>(Qh, Kh, Vt, Obf);
  out_kernel<<<dim3(64, 8), 256, 0, stream>>>(Obf, WoT, bo, out);
}

// Round 3
// 368.682 us; speedup vs baseline: 1.4045x; 1.2669x over previous
//
#include <hip/hip_runtime.h>

// ScaledDotProductAttention: B=4, NQ=NK=2048, D_MODEL=D_K=D_V=1024, H=16, HD=64.
// Full bf16-MFMA pipeline (fp32 accumulate everywhere):
//  1) transpose_cast_w : W* fp32 [K][N] -> bf16 [N][K]   (B^T layout for MFMA B-frags)
//  2) proj_kernel      : Q/K/V projections, 128x128 tile, BK=32; epilogue scatters to
//                        Qh/Kh [B,H,N,64] and Vt [B,H,64,N] with per-32-key column
//                        INTERLEAVE (pos = quad*8+j*4+r) so attn V-frags are 16B loads.
//                        Q is PRE-SCALED by (1/sqrt(1024))*log2(e).
//  3) attn_kernel      : transposed-S flash attention, register-resident P.
//                        R6: register K/V ping-pong was stall-bound (4 waves loaded
//                        identical tiles; 4x redundant VMEM). R7: block-shared LDS
//                        staging via global_load_lds, fragment-major (16 groups x 1KiB
//                        per 64-key tile), 4 gload_lds per wave per tile, double-
//                        buffered, T3 2-phase. R8: R7 ran with __launch_bounds__(256,4)
//                        -> allocator snapped to the 64-VGPR/8-waves class and SPILLED
//                        the ~100-VGPR live set in the hot loop (WRITE_SIZE 301MB vs
//                        16MB legit, 14.6k cy/iter vs ~600 arithmetic). Now (256,2):
//                        256-VGPR class, no spill (R1 precedent: 96 VGPR, WRITE=16MB).
//  4) out_kernel       : O @ Wo + bo -> fp32 d_out
// Workspace: 72 MiB total (offsets below).

#define DM    1024
#define NSEQ  2048
#define HEADS 16
#define HD    64

typedef float floatx4 __attribute__((ext_vector_type(4)));
typedef short s16x4   __attribute__((ext_vector_type(4)));
typedef short s16x8   __attribute__((ext_vector_type(8)));
typedef unsigned int u32x4 __attribute__((ext_vector_type(4)));

static __device__ __forceinline__ floatx4 mfma_bf16(s16x8 a, s16x8 b, floatx4 c) {
  return __builtin_amdgcn_mfma_f32_16x16x32_bf16(a, b, c, 0, 0, 0);
}

// Async global->LDS DMA, 16B per lane: dest = wave-uniform base + lane*16,
// source = per-lane global address.
static __device__ __forceinline__ void gload_lds16(const void* g, void* l) {
  __builtin_amdgcn_global_load_lds(
      (const __attribute__((address_space(1))) unsigned*)g,
      (__attribute__((address_space(3))) unsigned*)l, 16, 0, 0);
}

// fp32 -> bf16 round-to-nearest-even (bit trick; inputs are finite)
static __device__ __forceinline__ short f2bf(float f) {
  unsigned u = __builtin_bit_cast(unsigned, f);
  u += 0x7FFFu + ((u >> 16) & 1u);
  return (short)(u >> 16);
}

// Pack 2 fp32 -> 2 bf16 in one u32 (round-half-up: +0x8000, keep high halves).
static __device__ __forceinline__ unsigned pack2_bf16(float a, float b) {
  unsigned ua = __builtin_bit_cast(unsigned, a) + 0x8000u;
  unsigned ub = __builtin_bit_cast(unsigned, b) + 0x8000u;
#if __has_builtin(__builtin_amdgcn_perm)
  return __builtin_amdgcn_perm(ub, ua, 0x07060302u);  // lo=hi16(ua), hi=hi16(ub)
#else
  return (ub & 0xffff0000u) | (ua >> 16);
#endif
}

// ---------------------------------------------------------------------------
// 1) Weight transpose + cast: W [1024 k][1024 n] fp32 -> Wt [n][k] bf16
__global__ __launch_bounds__(256) void transpose_cast_w(
    const float* __restrict__ W0, const float* __restrict__ W1,
    const float* __restrict__ W2, const float* __restrict__ W3,
    short* __restrict__ T0, short* __restrict__ T1,
    short* __restrict__ T2, short* __restrict__ T3) {
  __shared__ float tile[32][33];
  const float* W = blockIdx.z == 0 ? W0 : blockIdx.z == 1 ? W1 : blockIdx.z == 2 ? W2 : W3;
  short*       T = blockIdx.z == 0 ? T0 : blockIdx.z == 1 ? T1 : blockIdx.z == 2 ? T2 : T3;
  const int bx = blockIdx.x * 32;  // n-offset
  const int by = blockIdx.y * 32;  // k-offset
  const int tx = threadIdx.x, ty = threadIdx.y;
  for (int i = 0; i < 4; i++)
    tile[ty + i * 8][tx] = W[(long)(by + ty + i * 8) * DM + bx + tx];
  __syncthreads();
  for (int i = 0; i < 4; i++)
    T[(long)(bx + ty + i * 8) * DM + by + tx] = f2bf(tile[tx][ty + i * 8]);
}

// ---------------------------------------------------------------------------
// 2) Projection GEMM: C[8192x1024] = A(fp32) @ W, A staged fp32->bf16.
//    z=0: queries->Qh (PRE-SCALED by log2e/sqrt(d_k)), z=1: keys->Kh, z=2: values->Vt
__global__ __launch_bounds__(256) void proj_kernel(
    const float* __restrict__ Aq, const float* __restrict__ Ak, const float* __restrict__ Av,
    const short* __restrict__ BtQ, const short* __restrict__ BtK, const short* __restrict__ BtV,
    short* __restrict__ Qh, short* __restrict__ Kh, short* __restrict__ Vt) {
  __shared__ short As[128 * 40];  // 128 rows x (32+8 pad) bf16
  __shared__ short Bs[128 * 40];
  const int z = blockIdx.z;
  const float* A  = z == 0 ? Aq  : z == 1 ? Ak  : Av;
  const short* Bt = z == 0 ? BtQ : z == 1 ? BtK : BtV;
  const int t = threadIdx.x;
  const int w = t >> 6, l = t & 63, quad = l >> 4, lm = l & 15;
  const int wm = w >> 1, wn = w & 1;
  const int row0 = blockIdx.x * 128, col0 = blockIdx.y * 128;

  floatx4 acc[4][4];
  for (int mi = 0; mi < 4; mi++)
    for (int ni = 0; ni < 4; ni++) acc[mi][ni] = (floatx4){0.f, 0.f, 0.f, 0.f};

  for (int k0 = 0; k0 < DM; k0 += 32) {
    for (int j = 0; j < 4; j++) {  // A tile: 128x32 fp32 -> bf16 LDS
      int idx = j * 256 + t;
      int row = idx >> 3, c4 = idx & 7;
      floatx4 v = *(const floatx4*)(A + (long)(row0 + row) * DM + k0 + c4 * 4);
      s16x4 hv = {f2bf(v[0]), f2bf(v[1]), f2bf(v[2]), f2bf(v[3])};
      *(s16x4*)(As + row * 40 + c4 * 4) = hv;
    }
    for (int j = 0; j < 2; j++) {  // B tile: 128x32 bf16
      int idx = j * 256 + t;
      int row = idx >> 2, ch = idx & 3;
      *(s16x8*)(Bs + row * 40 + ch * 8) =
          *(const s16x8*)(Bt + (long)(col0 + row) * DM + k0 + ch * 8);
    }
    __syncthreads();
    s16x8 af[4], bfr[4];
    for (int mi = 0; mi < 4; mi++)
      af[mi] = *(const s16x8*)(As + (wm * 64 + mi * 16 + lm) * 40 + quad * 8);
    for (int ni = 0; ni < 4; ni++)
      bfr[ni] = *(const s16x8*)(Bs + (wn * 64 + ni * 16 + lm) * 40 + quad * 8);
    for (int mi = 0; mi < 4; mi++)
      for (int ni = 0; ni < 4; ni++)
        acc[mi][ni] = mfma_bf16(af[mi], bfr[ni], acc[mi][ni]);
    __syncthreads();
  }

  const int rowbase = row0 + wm * 64;  // multiple of 64 -> single b per wave
  const int colbase = col0 + wn * 64;  // multiple of 64 -> single head per wave
  const int b = rowbase >> 11;
  const int h = colbase >> 6;
  const int rloc = rowbase & 2047;
  if (z < 2) {
    short* Out = z == 0 ? Qh : Kh;
    // Fold softmax scale * log2(e) into Q so attn uses exp2 with no multiply.
    const float osc = z == 0 ? 0.0450842200277801f : 1.0f;
    long base = ((long)(b * HEADS + h)) * NSEQ * HD;
    for (int mi = 0; mi < 4; mi++)
      for (int r = 0; r < 4; r++) {
        int q = rloc + mi * 16 + quad * 4 + r;
        long rowoff = base + (long)q * HD + lm;
        for (int ni = 0; ni < 4; ni++)
          Out[rowoff + ni * 16] = f2bf(acc[mi][ni][r] * osc);
      }
  } else {
    // Vt with per-32-key interleave: key kloc=(j*16+quad*4+r) within its 32-group
    // is stored at position quad*8 + j*4 + r, so attn reads one 16B chunk per
    // (d-row, quad) covering a full K=32 logical-k fragment.
    long base = ((long)(b * HEADS + h)) * HD * NSEQ;
    for (int mi = 0; mi < 4; mi++)
      for (int r = 0; r < 4; r++) {
        int kcol = rloc + (mi >> 1) * 32 + quad * 8 + (mi & 1) * 4 + r;
        for (int ni = 0; ni < 4; ni++)
          Vt[base + (long)(ni * 16 + lm) * NSEQ + kcol] = f2bf(acc[mi][ni][r]);
      }
  }
}

// ---------------------------------------------------------------------------
// 3) Transposed-S flash attention. Grid (bh=64, qy=16) -> XCD = bh%8 (L2 local).
//    4 waves/block, wave = 32 q-rows (2x16); K/V tile (64 keys) staged ONCE per
//    block in LDS (was: every wave loaded it redundantly).
//    LDS layout per tile buffer: 16 groups x 1KiB, fragment-major:
//      g = 0..7  : K frag group (s=g>>2, j=(g>>1)&1, c=g&1); chunk l holds the 16B
//                  K[kt+s*32+j*16+(l&15)][c*32+(l>>4)*8 ..+8]
//      g = 8..15 : V frag group (s=(g&7)>>2, n=g&3); chunk l holds the 16B
//                  Vt[n*16+(l&15)][kt+s*32+(l>>4)*8 ..+8]   (interleaved cols)
//    Staged via global_load_lds (dest = base+lane*16, per-lane source address),
//    4 instructions per wave per tile. ds_read_b128 back at group*1K + l*16:
//    linear in lane -> conflict-free. Double-buffered; stage(next) is issued
//    before process(cur) so the __syncthreads vmcnt drain is hidden (T3 2-phase).
//    R8: __launch_bounds__(256,2) -- the (256,4) build spilled ~100 live VGPRs
//    (allocator snapped to the 64-VGPR class: WRITE_SIZE 301MB of scratch).
__global__ __launch_bounds__(256, 2) void attn_kernel(
    const short* __restrict__ Qh, const short* __restrict__ Kh,
    const short* __restrict__ Vt, short* __restrict__ Obf) {
  __shared__ short lds[2 * 8192];  // 2 x 16KiB tile buffers; epilogue reuses buf0
  const int t = threadIdx.x;
  const int w = t >> 6, l = t & 63, quad = l >> 4, lm = l & 15;
  const int bh = blockIdx.x;    // b*16+h  (grid-x => XCD = bh%8: L2 locality)
  const int qtile = blockIdx.y * 128 + w * 32;
  const short* Qp = Qh + (long)bh * NSEQ * HD;
  const short* Kp = Kh + (long)bh * NSEQ * HD;
  const short* Vp = Vt + (long)bh * HD * NSEQ;

  s16x8 aq[2][2];  // Q-frags; serve as MFMA *B* operand for S^T (layout identical)
#pragma unroll
  for (int qi = 0; qi < 2; qi++)
#pragma unroll
    for (int c = 0; c < 2; c++)
      aq[qi][c] = *(const s16x8*)(Qp + (long)(qtile + qi * 16 + lm) * HD + c * 32 + quad * 8);

  floatx4 acc[2][4];  // O^T, C-layout: d = n*16+quad*4+reg, q = lm
  float lsum[2] = {0.f, 0.f};
#pragma unroll
  for (int qi = 0; qi < 2; qi++)
#pragma unroll
    for (int n = 0; n < 4; n++) acc[qi][n] = (floatx4){0.f, 0.f, 0.f, 0.f};

  // Stage the 64-key tile at kt into buffer `buf`. Wave w stages groups 4w..4w+3.
  auto stage = [&](int kt, int buf) __attribute__((always_inline)) {
    short* base = lds + buf * 8192;
#pragma unroll
    for (int i = 0; i < 4; i++) {
      int g = w * 4 + i;
      const short* src;
      if (w < 2) {  // K groups 0..7
        int s = (g >> 2) & 1, j = (g >> 1) & 1, c = g & 1;
        src = Kp + (long)(kt + s * 32 + j * 16 + lm) * HD + c * 32 + quad * 8;
      } else {      // V groups 8..15
        int gg = g & 7;
        int s = gg >> 2, n = gg & 3;
        src = Vp + (long)(n * 16 + lm) * NSEQ + kt + s * 32 + quad * 8;
      }
      gload_lds16(src, base + g * 512);
    }
  };

  // Process one 32-key subtile (s = 0/1) from tile buffer Lb.
  auto process = [&](const short* Lb, int s) __attribute__((always_inline)) {
    s16x8 bk[2][2];
#pragma unroll
    for (int j = 0; j < 2; j++)
#pragma unroll
      for (int c = 0; c < 2; c++)
        bk[j][c] = *(const s16x8*)(Lb + ((s * 4 + j * 2 + c) * 64 + l) * 8);
    s16x8 vraw[4];
#pragma unroll
    for (int n = 0; n < 4; n++)
      vraw[n] = *(const s16x8*)(Lb + ((8 + s * 4 + n) * 64 + l) * 8);
#pragma unroll
    for (int qi = 0; qi < 2; qi++) {
      floatx4 sT[2];
      sT[0] = (floatx4){0.f, 0.f, 0.f, 0.f};
      sT[1] = (floatx4){0.f, 0.f, 0.f, 0.f};
      __builtin_amdgcn_s_setprio(1);
#pragma unroll
      for (int c = 0; c < 2; c++) {
        sT[0] = mfma_bf16(bk[0][c], aq[qi][c], sT[0]);
        sT[1] = mfma_bf16(bk[1][c], aq[qi][c], sT[1]);
      }
      __builtin_amdgcn_s_setprio(0);
      float p0 = __builtin_amdgcn_exp2f(sT[0][0]);
      float p1 = __builtin_amdgcn_exp2f(sT[0][1]);
      float p2 = __builtin_amdgcn_exp2f(sT[0][2]);
      float p3 = __builtin_amdgcn_exp2f(sT[0][3]);
      float p4 = __builtin_amdgcn_exp2f(sT[1][0]);
      float p5 = __builtin_amdgcn_exp2f(sT[1][1]);
      float p6 = __builtin_amdgcn_exp2f(sT[1][2]);
      float p7 = __builtin_amdgcn_exp2f(sT[1][3]);
      lsum[qi] += ((p0 + p1) + (p2 + p3)) + ((p4 + p5) + (p6 + p7));
      u32x4 pw = {pack2_bf16(p0, p1), pack2_bf16(p2, p3),
                  pack2_bf16(p4, p5), pack2_bf16(p6, p7)};
      s16x8 pcat = __builtin_bit_cast(s16x8, pw);
      __builtin_amdgcn_s_setprio(1);
#pragma unroll
      for (int n = 0; n < 4; n++)
        acc[qi][n] = mfma_bf16(vraw[n], pcat, acc[qi][n]);
      __builtin_amdgcn_s_setprio(0);
    }
  };

  stage(0, 0);
  __syncthreads();  // compiler-emitted vmcnt(0) drain + s_barrier: tile 0 ready
  int cur = 0;
  for (int kt = 0; kt < NSEQ; kt += 64) {
    if (kt + 64 < NSEQ) stage(kt + 64, cur ^ 1);  // issue DMA, then compute
    const short* Lb = lds + cur * 8192;
    process(Lb, 0);
    process(Lb, 1);
    __syncthreads();  // drain (hidden under process) + cross-wave visibility
    cur ^= 1;
  }

  // lsum is per-lane over this lane's keys; full row sum = reduce across quads.
  const int b = bh >> 4, h = bh & 15;
  short* Ow = lds + w * 1152;  // reuse buf0 (final iter read buf1; regions disjoint)
  const int erow = l >> 2, ecg = l & 3;  // epilogue read/store mapping
#pragma unroll
  for (int qi = 0; qi < 2; qi++) {
    float ls = lsum[qi];
    ls += __shfl_xor(ls, 16);
    ls += __shfl_xor(ls, 32);
    float rl = 1.0f / ls;  // row sum for q = lm (same for all regs)
#pragma unroll
    for (int n = 0; n < 4; n++)
#pragma unroll
      for (int r = 0; r < 4; r++)
        Ow[lm * 72 + n * 16 + quad * 4 + r] = f2bf(acc[qi][n][r] * rl);
    // read back row-major (same wave; compiler inserts lgkmcnt wait), store coalesced
    s16x8 o0 = *(const s16x8*)(Ow + erow * 72 + ecg * 16);
    s16x8 o1 = *(const s16x8*)(Ow + erow * 72 + ecg * 16 + 8);
    long gaddr = ((long)(b * NSEQ + qtile + qi * 16 + erow)) * DM + h * HD + ecg * 16;
    *(s16x8*)(Obf + gaddr) = o0;
    *(s16x8*)(Obf + gaddr + 8) = o1;
  }
}

// ---------------------------------------------------------------------------
// 4) Output GEMM: d_out = Obf(bf16) @ WoT + bo, fp32 out
__global__ __launch_bounds__(256) void out_kernel(
    const short* __restrict__ Ab, const short* __restrict__ Bt,
    const float* __restrict__ bias, float* __restrict__ Out) {
  __shared__ short As[128 * 40];
  __shared__ short Bs[128 * 40];
  const int t = threadIdx.x;
  const int w = t >> 6, l = t & 63, quad = l >> 4, lm = l & 15;
  const int wm = w >> 1, wn = w & 1;
  const int row0 = blockIdx.x * 128, col0 = blockIdx.y * 128;

  floatx4 acc[4][4];
  for (int mi = 0; mi < 4; mi++)
    for (int ni = 0; ni < 4; ni++) acc[mi][ni] = (floatx4){0.f, 0.f, 0.f, 0.f};

  for (int k0 = 0; k0 < DM; k0 += 32) {
    for (int j = 0; j < 2; j++) {
      int idx = j * 256 + t;
      int row = idx >> 2, ch = idx & 3;
      *(s16x8*)(As + row * 40 + ch * 8) =
          *(const s16x8*)(Ab + (long)(row0 + row) * DM + k0 + ch * 8);
    }
    for (int j = 0; j < 2; j++) {
      int idx = j * 256 + t;
      int row = idx >> 2, ch = idx & 3;
      *(s16x8*)(Bs + row * 40 + ch * 8) =
          *(const s16x8*)(Bt + (long)(col0 + row) * DM + k0 + ch * 8);
    }
    __syncthreads();
    s16x8 af[4], bfr[4];
    for (int mi = 0; mi < 4; mi++)
      af[mi] = *(const s16x8*)(As + (wm * 64 + mi * 16 + lm) * 40 + quad * 8);
    for (int ni = 0; ni < 4; ni++)
      bfr[ni] = *(const s16x8*)(Bs + (wn * 64 + ni * 16 + lm) * 40 + quad * 8);
    for (int mi = 0; mi < 4; mi++)
      for (int ni = 0; ni < 4; ni++)
        acc[mi][ni] = mfma_bf16(af[mi], bfr[ni], acc[mi][ni]);
    __syncthreads();
  }

  const int rowbase = row0 + wm * 64;
  const int colbase = col0 + wn * 64;
  for (int mi = 0; mi < 4; mi++)
    for (int r = 0; r < 4; r++) {
      int gr = rowbase + mi * 16 + quad * 4 + r;
      for (int ni = 0; ni < 4; ni++) {
        int gc = colbase + ni * 16 + lm;
        Out[(long)gr * DM + gc] = acc[mi][ni][r] + bias[gc];
      }
    }
}

// ---------------------------------------------------------------------------
extern "C" void kernel_launch(void* const* d_in, const int* in_sizes, int n_in,
                              void* d_out, int out_size, void* d_ws, size_t ws_size,
                              hipStream_t stream) {
  (void)in_sizes; (void)n_in; (void)out_size; (void)ws_size;
  const float* queries = (const float*)d_in[0];
  const float* keys    = (const float*)d_in[1];
  const float* values  = (const float*)d_in[2];
  const float* Wq = (const float*)d_in[3];
  const float* Wk = (const float*)d_in[4];
  const float* Wv = (const float*)d_in[5];
  const float* Wo = (const float*)d_in[6];
  const float* bo = (const float*)d_in[7];
  float* out = (float*)d_out;

  char* ws = (char*)d_ws;
  const size_t MB = 1024 * 1024;
  short* WqT = (short*)(ws + 0 * MB);   // 2 MiB each
  short* WkT = (short*)(ws + 2 * MB);
  short* WvT = (short*)(ws + 4 * MB);
  short* WoT = (short*)(ws + 6 * MB);
  short* Qh  = (short*)(ws + 8 * MB);   // [B,H,2048,64] bf16 = 16 MiB
  short* Kh  = (short*)(ws + 24 * MB);  // 16 MiB
  short* Vt  = (short*)(ws + 40 * MB);  // [B,H,64,2048] bf16 (interleaved cols) = 16 MiB
  short* Obf = (short*)(ws + 56 * MB);  // [8192,1024] bf16 = 16 MiB  (total 72 MiB)

  transpose_cast_w<<<dim3(32, 32, 4), dim3(32, 8), 0, stream>>>(
      Wq, Wk, Wv, Wo, WqT, WkT, WvT, WoT);
  proj_kernel<<<dim3(64, 8, 3), 256, 0, stream>>>(
      queries, keys, values, WqT, WkT, WvT, Qh, Kh, Vt);
  attn_kernel<<<dim3(64, 16), 256, 0, stream>>>(Qh, Kh, Vt, Obf);
  out_kernel<<<dim3(64, 8), 256, 0, stream>>>(Obf, WoT, bo, out);
}